// Round 6
// baseline (173.051 us; speedup 1.0000x reference)
//
#include <hip/hip_runtime.h>
#include <stdint.h>

typedef float  f32x4 __attribute__((ext_vector_type(4)));
typedef short  s16x8 __attribute__((ext_vector_type(8)));
typedef unsigned short u16x4 __attribute__((ext_vector_type(4)));

constexpr int D      = 64;     // feature dim (fixed by problem)
constexpr int SPLITS = 64;     // M-dimension chunks; CH = 512
constexpr int ROWS_B = 256;    // source rows per block (4 groups of 64/wave-part)

__device__ __forceinline__ unsigned short f2bf(float f) {
    unsigned int u = __float_as_uint(f);
    u = (u + 0x7FFFu + ((u >> 16) & 1u)) >> 16;
    return (unsigned short)u;
}

// ---- prep: Yb = bf16(-2*y); t[m] = ||y||^2 - psi[m]; psum += block psi sum
__global__ void prep_targets(const float* __restrict__ Y,
                             const float* __restrict__ psi,
                             unsigned short* __restrict__ Yb,
                             float* __restrict__ t,
                             float* __restrict__ psum) {
    const int tid  = threadIdx.x;
    const int lane = tid & 63;
    const int wave = tid >> 6;
    const int sub  = lane >> 4;
    const int l16  = lane & 15;
    const int row  = blockIdx.x * 16 + wave * 4 + sub;

    const float4 v = *reinterpret_cast<const float4*>(Y + row * D + l16 * 4);
    u16x4 o;
    o[0] = f2bf(-2.f * v.x); o[1] = f2bf(-2.f * v.y);
    o[2] = f2bf(-2.f * v.z); o[3] = f2bf(-2.f * v.w);
    *reinterpret_cast<u16x4*>(Yb + row * D + l16 * 4) = o;

    float s = v.x * v.x + v.y * v.y + v.z * v.z + v.w * v.w;
    #pragma unroll
    for (int off = 1; off <= 8; off <<= 1) s += __shfl_xor(s, off);

    float p = 0.f;
    if (l16 == 0) { p = psi[row]; t[row] = s - p; }
    p += __shfl_xor(p, 16);
    p += __shfl_xor(p, 32);

    __shared__ float ps[4];
    if (lane == 0) ps[wave] = p;
    __syncthreads();
    if (tid == 0) atomicAdd(psum, ps[0] + ps[1] + ps[2] + ps[3]);
}

// ---- main: barrier-free B-streaming fused MFMA + running-min.
// grid=(SPLITS, N/ROWS_B), block=256 (4 waves). Each wave: 64 source rows in
// A-frags (R=4), streams 16 targets/iter from global (L1/L2-resident Yb, 4MB)
// into B-frags with 1-deep register prefetch. No LDS, no __syncthreads in the
// hot loop -> no vmcnt(0) barrier drains. Yb pre-scaled by -2; first MFMA of
// each chain reads C = t[m] broadcast, so acc = ||y||^2 - psi - 2<x,y>.
// NOTE: last iteration prefetches 16 rows past the chunk; for the final chunk
// this reads the t/partial arrays (still inside d_ws) — values are discarded.
__global__ __launch_bounds__(256, 4)
void sdot_main(const float* __restrict__ X,
               const unsigned short* __restrict__ Yb,
               const float* __restrict__ t,
               float* __restrict__ partial,
               int M, int N) {
    const int tid  = threadIdx.x;
    const int wave = tid >> 6;
    const int lane = tid & 63;
    const int quad = lane >> 4;
    const int r16  = lane & 15;
    const int chunk   = blockIdx.x;
    const int rowgrp  = blockIdx.y;
    const int CH      = M / SPLITS;
    const int m_begin = chunk * CH;
    const int NIT     = CH / 16;

    // A-frags: 4 groups x 2 K-halves; A[m=lane&15][k=quad*8+j]
    s16x8 a[4][2];
    #pragma unroll
    for (int g = 0; g < 4; g++) {
        const int srow = rowgrp * ROWS_B + g * 64 + wave * 16 + r16;
        #pragma unroll
        for (int h = 0; h < 2; h++) {
            const float4 u0 = *reinterpret_cast<const float4*>(X + srow * D + h * 32 + quad * 8);
            const float4 u1 = *reinterpret_cast<const float4*>(X + srow * D + h * 32 + quad * 8 + 4);
            s16x8 fr;
            fr[0] = (short)f2bf(u0.x); fr[1] = (short)f2bf(u0.y);
            fr[2] = (short)f2bf(u0.z); fr[3] = (short)f2bf(u0.w);
            fr[4] = (short)f2bf(u1.x); fr[5] = (short)f2bf(u1.y);
            fr[6] = (short)f2bf(u1.z); fr[7] = (short)f2bf(u1.w);
            a[g][h] = fr;
        }
    }

    float rmin[4][4];
    #pragma unroll
    for (int g = 0; g < 4; g++)
        #pragma unroll
        for (int r = 0; r < 4; r++) rmin[g][r] = 1e30f;

    // B stream base: lane covers target row (mb + r16), K-cols quad*8..+7 (b0)
    // and 32+quad*8..+7 (b1). All 4 waves of the block read the same rows -> L1 reuse.
    const unsigned short* yb = Yb + (size_t)(m_begin + r16) * D + quad * 8;
    const float* tp = t + m_begin + r16;

    s16x8 b0 = *reinterpret_cast<const s16x8*>(yb);
    s16x8 b1 = *reinterpret_cast<const s16x8*>(yb + 32);
    float tv = *tp;

    for (int it = 0; it < NIT; ++it) {
        // prefetch next 16-target group (registers; overlaps MFMAs below)
        const unsigned short* ybn = yb + (size_t)(it + 1) * (16 * D);
        const s16x8 nb0 = *reinterpret_cast<const s16x8*>(ybn);
        const s16x8 nb1 = *reinterpret_cast<const s16x8*>(ybn + 32);
        const float ntv = tp[(it + 1) * 16];

        const f32x4 tvv = {tv, tv, tv, tv};
        #pragma unroll
        for (int g = 0; g < 4; g++) {
            f32x4 acc = __builtin_amdgcn_mfma_f32_16x16x32_bf16(a[g][0], b0, tvv, 0, 0, 0);
            acc       = __builtin_amdgcn_mfma_f32_16x16x32_bf16(a[g][1], b1, acc, 0, 0, 0);
            #pragma unroll
            for (int r = 0; r < 4; r++)
                rmin[g][r] = fminf(rmin[g][r], acc[r]);
        }
        b0 = nb0; b1 = nb1; tv = ntv;
    }

    // min across the 16 columns (targets); C/D: col=lane&15, row=quad*4+reg
    #pragma unroll
    for (int off = 1; off <= 8; off <<= 1)
        #pragma unroll
        for (int g = 0; g < 4; g++)
            #pragma unroll
            for (int r = 0; r < 4; r++)
                rmin[g][r] = fminf(rmin[g][r], __shfl_xor(rmin[g][r], off));

    if (r16 == 0) {
        #pragma unroll
        for (int g = 0; g < 4; g++) {
            const int rowbase = rowgrp * ROWS_B + g * 64 + wave * 16 + quad * 4;
            #pragma unroll
            for (int r = 0; r < 4; r++)
                partial[(size_t)chunk * N + rowbase + r] = rmin[g][r];
        }
    }
}

// ---- finalize: out[n] = ||x_n||^2 + psum/M + min over SPLITS partials
__global__ void finalize(const float* __restrict__ X,
                         const float* __restrict__ partial,
                         const float* __restrict__ psum,
                         float* __restrict__ out, int N, float invM) {
    const int lane = threadIdx.x & 63;
    const int wave = threadIdx.x >> 6;
    const int row  = blockIdx.x * 4 + wave;
    const float x = X[row * D + lane];
    float s = x * x;
    #pragma unroll
    for (int off = 1; off <= 32; off <<= 1) s += __shfl_xor(s, off);
    float pm = partial[(size_t)lane * N + row];   // SPLITS == 64 == wave size
    #pragma unroll
    for (int off = 1; off <= 32; off <<= 1) pm = fminf(pm, __shfl_xor(pm, off));
    if (lane == 0) out[row] = s + pm + psum[0] * invM;
}

extern "C" void kernel_launch(void* const* d_in, const int* in_sizes, int n_in,
                              void* d_out, int out_size, void* d_ws, size_t ws_size,
                              hipStream_t stream) {
    const float* X   = (const float*)d_in[0];   // [N, 64]
    const float* Y   = (const float*)d_in[1];   // [M, 64]
    const float* psi = (const float*)d_in[2];   // [M]
    float* out = (float*)d_out;

    const int N = in_sizes[0] / D;   // 8192
    const int M = in_sizes[2];       // 32768

    char* ws = (char*)d_ws;
    unsigned short* Yb = (unsigned short*)ws;                 // M*64 bf16  (4 MB)
    size_t off = (size_t)M * D * sizeof(unsigned short);
    float* t = (float*)(ws + off);                            // M floats   (128 KB)
    off += (size_t)M * sizeof(float);
    float* partial = (float*)(ws + off);                      // SPLITS*N   (2 MB)
    off += (size_t)SPLITS * N * sizeof(float);
    float* psum = (float*)(ws + off);                         // 1 float

    hipMemsetAsync(psum, 0, sizeof(float), stream);
    prep_targets<<<M / 16, 256, 0, stream>>>(Y, psi, Yb, t, psum);
    dim3 grid(SPLITS, N / ROWS_B);
    sdot_main<<<grid, 256, 0, stream>>>(X, Yb, t, partial, M, N);
    finalize<<<N / 4, 256, 0, stream>>>(X, partial, psum, out, N, 1.0f / (float)M);
}